// Round 1
// baseline (515.035 us; speedup 1.0000x reference)
//
#include <hip/hip_runtime.h>

// m_btabl: per-sample (x:[40,10]) ->
//   h = relu(W1a @ (x @ W2a) + B)  [120,5]   (reassociated, exact same math up to fp reorder)
//   X = W1b @ h                    [3,5]
//   A = softmax_rows(X @ Wm), Wm = s*Tw off-diag, 1/5 diag
//   Xc = lam*X + (1-lam)*X*A ; y = Xc @ W2b + TB ; out = softmax(y over 3)
// Mapping: 256 thr/block, 2 threads per sample (p = tid&1 owns d-rows [p*20, p*20+20)),
// 128 samples/block. Weights max-norm'd + staged in LDS per block.

#define NT 256

__device__ inline float block_reduce_sum(float v, float* red, int tid) {
    #pragma unroll
    for (int off = 32; off > 0; off >>= 1)
        v += __shfl_xor(v, off, 64);
    if ((tid & 63) == 0) red[tid >> 6] = v;
    __syncthreads();
    float r = red[0] + red[1] + red[2] + red[3];
    __syncthreads();   // red reused by next reduction
    return r;
}

__global__ __launch_bounds__(NT)
void btabl_kernel(const float* __restrict__ x,
                  const float* __restrict__ W1,  // [120,40]
                  const float* __restrict__ W2,  // [10,5]
                  const float* __restrict__ B,   // [120,5]
                  const float* __restrict__ Tw1, // [3,120]
                  const float* __restrict__ Tw,  // [5,5]
                  const float* __restrict__ Tw2, // [5,1]
                  const float* __restrict__ TB,  // [3,1]
                  const float* __restrict__ l,   // [1]
                  float* __restrict__ out,       // [B,3]
                  int nsamp)
{
    __shared__ float sW1[120*40];   // scaled
    __shared__ float sB[120*5];
    __shared__ float sW1b[120*3];   // transposed [e][j], scaled
    __shared__ float sW2[10*5];     // scaled
    __shared__ float sWm[25];
    __shared__ float sW2b[5];
    __shared__ float sTB[3];
    __shared__ float sLam[1];
    __shared__ float red[4];

    const int tid = threadIdx.x;

    // ---- max_norm scales (redundant per block; tiny) ----
    float ss;
    ss = 0.f; for (int i = tid; i < 4800; i += NT) { float w = W1[i];  ss += w*w; }
    float n1 = sqrtf(block_reduce_sum(ss, red, tid));
    ss = 0.f; for (int i = tid; i < 50;   i += NT) { float w = W2[i];  ss += w*w; }
    float n2 = sqrtf(block_reduce_sum(ss, red, tid));
    ss = 0.f; for (int i = tid; i < 360;  i += NT) { float w = Tw1[i]; ss += w*w; }
    float n3 = sqrtf(block_reduce_sum(ss, red, tid));
    ss = 0.f; for (int i = tid; i < 25;   i += NT) { float w = Tw[i];  ss += w*w; }
    float n4 = sqrtf(block_reduce_sum(ss, red, tid));
    ss = 0.f; for (int i = tid; i < 5;    i += NT) { float w = Tw2[i]; ss += w*w; }
    float n5 = sqrtf(block_reduce_sum(ss, red, tid));

    const float s1 = n1 > 10.f ? 10.f/(1e-8f+n1) : 1.f;
    const float s2 = n2 > 10.f ? 10.f/(1e-8f+n2) : 1.f;
    const float s3 = n3 > 10.f ? 10.f/(1e-8f+n3) : 1.f;
    const float s4 = n4 > 10.f ? 10.f/(1e-8f+n4) : 1.f;
    const float s5 = n5 > 10.f ? 10.f/(1e-8f+n5) : 1.f;

    // ---- stage weights into LDS ----
    for (int i = tid; i < 4800; i += NT) sW1[i] = W1[i]*s1;
    for (int i = tid; i < 600;  i += NT) sB[i]  = B[i];
    for (int i = tid; i < 360;  i += NT) { int j = i/120, e = i%120; sW1b[e*3+j] = Tw1[i]*s3; }
    for (int i = tid; i < 50;   i += NT) sW2[i] = W2[i]*s2;
    for (int i = tid; i < 25;   i += NT) { int r = i/5, c = i%5; sWm[i] = (r==c) ? 0.2f : Tw[i]*s4; }
    if (tid < 5) sW2b[tid] = Tw2[tid]*s5;
    if (tid < 3) sTB[tid]  = TB[tid];
    if (tid == 0) { float lv = l[0]; sLam[0] = lv < 0.f ? 0.f : (lv > 1.f ? 1.f : lv); }
    __syncthreads();

    const int pair = tid >> 1;
    const int p    = tid & 1;
    const long long s = (long long)blockIdx.x * 128 + pair;
    if (s >= nsamp) return;   // no __syncthreads past this point

    const float* xs = x + s*400 + p*200;   // this thread's 20 rows of 10

    // W2 (50 floats) into registers for stage 1
    float w2r[50];
    #pragma unroll
    for (int i = 0; i < 50; i++) w2r[i] = sW2[i];

    // ---- stage 1: Z = x_chunk @ W2s  -> Z[20][5] in registers ----
    float Z[20][5];
    #pragma unroll
    for (int d0 = 0; d0 < 20; d0 += 2) {
        const float4* xv = (const float4*)(xs + d0*10);   // 80B-aligned (d0 even)
        float4 f0 = xv[0], f1 = xv[1], f2 = xv[2], f3 = xv[3], f4 = xv[4];
        float v[20] = {f0.x,f0.y,f0.z,f0.w, f1.x,f1.y,f1.z,f1.w,
                       f2.x,f2.y,f2.z,f2.w, f3.x,f3.y,f3.z,f3.w,
                       f4.x,f4.y,f4.z,f4.w};
        #pragma unroll
        for (int r = 0; r < 2; r++) {
            #pragma unroll
            for (int t = 0; t < 5; t++) {
                float a = 0.f;
                #pragma unroll
                for (int k = 0; k < 10; k++) a += v[r*10+k]*w2r[k*5+t];
                Z[d0+r][t] = a;
            }
        }
    }

    // ---- stage 2: X3 = W1b @ relu(W1 @ Z + B), pair-split over d ----
    float X3[15];
    #pragma unroll
    for (int i = 0; i < 15; i++) X3[i] = 0.f;

    for (int e = 0; e < 120; e++) {
        float acc[5] = {0.f,0.f,0.f,0.f,0.f};
        const float4* wr = (const float4*)(&sW1[e*40 + p*20]);  // 16B-aligned
        #pragma unroll
        for (int c = 0; c < 5; c++) {
            float4 w = wr[c];
            #pragma unroll
            for (int t = 0; t < 5; t++)
                acc[t] += w.x*Z[c*4+0][t] + w.y*Z[c*4+1][t]
                        + w.z*Z[c*4+2][t] + w.w*Z[c*4+3][t];
        }
        // reduce the two half-sums of this sample (lanes 2i, 2i+1)
        #pragma unroll
        for (int t = 0; t < 5; t++) acc[t] += __shfl_xor(acc[t], 1, 64);

        const float w1b0 = sW1b[e*3+0], w1b1 = sW1b[e*3+1], w1b2 = sW1b[e*3+2];
        #pragma unroll
        for (int t = 0; t < 5; t++) {
            float h = acc[t] + sB[e*5+t];
            h = fmaxf(h, 0.f);
            X3[t]    += w1b0*h;
            X3[5+t]  += w1b1*h;
            X3[10+t] += w1b2*h;
        }
    }

    // ---- stage 3: attention + output softmax (duplicated in both pair lanes) ----
    const float lam = sLam[0];
    float y[3];
    #pragma unroll
    for (int j = 0; j < 3; j++) {
        float Sr[5];
        #pragma unroll
        for (int t = 0; t < 5; t++) {
            float a = 0.f;
            #pragma unroll
            for (int k = 0; k < 5; k++) a += X3[j*5+k]*sWm[k*5+t];
            Sr[t] = a;
        }
        float m = Sr[0];
        #pragma unroll
        for (int t = 1; t < 5; t++) m = fmaxf(m, Sr[t]);
        float ex[5], se = 0.f;
        #pragma unroll
        for (int t = 0; t < 5; t++) { ex[t] = __expf(Sr[t]-m); se += ex[t]; }
        const float inv = 1.f/se;
        float yj = sTB[j];
        #pragma unroll
        for (int t = 0; t < 5; t++) {
            float a  = ex[t]*inv;
            float xc = X3[j*5+t]*(lam + (1.f-lam)*a);
            yj += xc*sW2b[t];
        }
        y[j] = yj;
    }
    float m  = fmaxf(y[0], fmaxf(y[1], y[2]));
    float e0 = __expf(y[0]-m), e1 = __expf(y[1]-m), e2 = __expf(y[2]-m);
    float inv = 1.f/(e0+e1+e2);
    if (p == 0) {
        float* o = out + s*3;
        o[0] = e0*inv; o[1] = e1*inv; o[2] = e2*inv;
    }
}

extern "C" void kernel_launch(void* const* d_in, const int* in_sizes, int n_in,
                              void* d_out, int out_size, void* d_ws, size_t ws_size,
                              hipStream_t stream) {
    const float* x   = (const float*)d_in[0];
    const float* W1  = (const float*)d_in[1];
    const float* W2  = (const float*)d_in[2];
    const float* B   = (const float*)d_in[3];
    const float* Tw1 = (const float*)d_in[4];
    const float* Tw  = (const float*)d_in[5];
    const float* Tw2 = (const float*)d_in[6];
    const float* TB  = (const float*)d_in[7];
    const float* l   = (const float*)d_in[8];
    float* out = (float*)d_out;

    const int nsamp = in_sizes[0] / 400;
    const int grid  = (nsamp + 127) / 128;
    hipLaunchKernelGGL(btabl_kernel, dim3(grid), dim3(NT), 0, stream,
                       x, W1, W2, B, Tw1, Tw, Tw2, TB, l, out, nsamp);
}

// Round 2
// 410.290 us; speedup vs baseline: 1.2553x; 1.2553x over previous
//
#include <hip/hip_runtime.h>

// m_btabl — round 2.
// prep_kernel: max_norm all weights once, write packed scaled weights to d_ws:
//   [0 .. 5808)  : 121 records x 48 floats: rec e = [W1s[e][0..39] | B[e][0..4] | W1b_s[e][0..2]]
//                  (record 120 = zeros, prefetch target only)
//   [5824..5876) : W2s 50 floats + 2 pad
//   [5888..5924) : stage-3 consts: Wm(25) | W2b_s(5) | TB(3) | lam | 2 pad
// btabl_main: 2 threads/sample (pair splits d 0..19 / 20..39).
//   W1 row halves from LDS (ds_read_b128, lane-divergent).
//   B/W1b/W2/stage-3 consts from SGPRs via s_load (wave-uniform) -> no LDS/VGPR cost.
//   Pair reduction via DPP quad_perm (VALU) instead of ds_swizzle (DS pipe).

typedef float f32x16 __attribute__((ext_vector_type(16)));
typedef float f32x8  __attribute__((ext_vector_type(8)));
typedef float f32x4t __attribute__((ext_vector_type(4)));

#define NT 256

// ---------------- prep kernel (1 block) ----------------
__device__ __forceinline__ float block_reduce_sum(float v, float* red, int tid) {
    #pragma unroll
    for (int off = 32; off > 0; off >>= 1) v += __shfl_xor(v, off, 64);
    if ((tid & 63) == 0) red[tid >> 6] = v;
    __syncthreads();
    float r = red[0] + red[1] + red[2] + red[3];
    __syncthreads();
    return r;
}

__global__ __launch_bounds__(NT)
void prep_kernel(const float* __restrict__ W1, const float* __restrict__ W2,
                 const float* __restrict__ B,  const float* __restrict__ Tw1,
                 const float* __restrict__ Tw, const float* __restrict__ Tw2,
                 const float* __restrict__ TB, const float* __restrict__ l,
                 float* __restrict__ ws)
{
    __shared__ float red[4];
    const int tid = threadIdx.x;
    float ss;
    ss = 0.f; for (int i = tid; i < 4800; i += NT) { float w = W1[i];  ss += w*w; }
    const float n1 = sqrtf(block_reduce_sum(ss, red, tid));
    ss = 0.f; for (int i = tid; i < 50;   i += NT) { float w = W2[i];  ss += w*w; }
    const float n2 = sqrtf(block_reduce_sum(ss, red, tid));
    ss = 0.f; for (int i = tid; i < 360;  i += NT) { float w = Tw1[i]; ss += w*w; }
    const float n3 = sqrtf(block_reduce_sum(ss, red, tid));
    ss = 0.f; for (int i = tid; i < 25;   i += NT) { float w = Tw[i];  ss += w*w; }
    const float n4 = sqrtf(block_reduce_sum(ss, red, tid));
    ss = 0.f; for (int i = tid; i < 5;    i += NT) { float w = Tw2[i]; ss += w*w; }
    const float n5 = sqrtf(block_reduce_sum(ss, red, tid));

    const float s1 = n1 > 10.f ? 10.f/(1e-8f+n1) : 1.f;
    const float s2 = n2 > 10.f ? 10.f/(1e-8f+n2) : 1.f;
    const float s3 = n3 > 10.f ? 10.f/(1e-8f+n3) : 1.f;
    const float s4 = n4 > 10.f ? 10.f/(1e-8f+n4) : 1.f;
    const float s5 = n5 > 10.f ? 10.f/(1e-8f+n5) : 1.f;

    for (int i = tid; i < 4800; i += NT) { int e = i/40,  d = i - e*40;  ws[e*48+d]      = W1[i]*s1; }
    for (int i = tid; i < 600;  i += NT) { int e = i/5,   t = i - e*5;   ws[e*48+40+t]   = B[i];     }
    for (int i = tid; i < 360;  i += NT) { int j = i/120, e = i - j*120; ws[e*48+45+j]   = Tw1[i]*s3;}
    for (int i = tid; i < 48;   i += NT) ws[120*48 + i] = 0.f;                    // prefetch pad rec
    for (int i = tid; i < 52;   i += NT) ws[5824 + i] = (i < 50) ? W2[i]*s2 : 0.f;
    for (int i = tid; i < 36;   i += NT) {
        float v = 0.f;
        if (i < 25)      { int r = i/5, c = i - r*5; v = (r==c) ? 0.2f : Tw[i]*s4; }
        else if (i < 30) v = Tw2[i-25]*s5;
        else if (i < 33) v = TB[i-30];
        else if (i == 33){ float lv = l[0]; v = fminf(fmaxf(lv, 0.f), 1.f); }
        ws[5888 + i] = v;
    }
}

// ---------------- main kernel ----------------
__device__ __forceinline__ float pair_sum(float v) {
    // quad_perm [1,0,3,2]: swap lanes 2i <-> 2i+1 (VALU DPP, stays off the DS pipe)
    int o = __builtin_amdgcn_update_dpp(0, __float_as_int(v), 0xB1, 0xF, 0xF, true);
    return v + __int_as_float(o);
}

__device__ __forceinline__ float w2f(const f32x16& a, const f32x16& b,
                                     const f32x16& c, const f32x4t& d, int i) {
    return i < 16 ? a[i] : i < 32 ? b[i-16] : i < 48 ? c[i-32] : d[i-48];
}
__device__ __forceinline__ float c3f(const f32x16& a, const f32x16& b,
                                     const f32x4t& c, int i) {
    return i < 16 ? a[i] : i < 32 ? b[i-16] : c[i-32];
}

__global__ __launch_bounds__(NT, 3)
void btabl_main(const float* __restrict__ x, const float* __restrict__ ws,
                float* __restrict__ out, int nsamp)
{
    __shared__ float sRec[5808];   // 121 records x 48 floats, 23.2 KB

    const int tid = threadIdx.x;
    {   // stage full packed records into LDS (unit-stride float4, coalesced)
        const float4* src = (const float4*)ws;
        float4* dst = (float4*)sRec;
        for (int i = tid; i < 1452; i += NT) dst[i] = src[i];
    }
    __syncthreads();

    // W2 -> SGPRs (wave-uniform)
    f32x16 wa, wb, wc; f32x4t wd;
    {
        const float* w2p = ws + 5824;
        asm volatile("s_load_dwordx16 %0, %4, 0x0\n\t"
                     "s_load_dwordx16 %1, %4, 0x40\n\t"
                     "s_load_dwordx16 %2, %4, 0x80\n\t"
                     "s_load_dwordx4  %3, %4, 0xc0\n\t"
                     "s_waitcnt lgkmcnt(0)"
                     : "=&s"(wa), "=&s"(wb), "=&s"(wc), "=&s"(wd)
                     : "s"(w2p));
    }

    const int pair = tid >> 1;
    const int p    = tid & 1;
    const int s    = blockIdx.x * 128 + pair;
    if (s >= nsamp) return;

    const float* xs = x + (size_t)s*400 + p*200;   // this lane's 20 rows of 10

    // ---- stage 1: Z = x_half @ W2s -> Z[20][5] in registers, W2 from SGPR ----
    float Z[20][5];
    #pragma unroll
    for (int d0 = 0; d0 < 20; d0 += 2) {
        const float4* xv = (const float4*)(xs + d0*10);   // 16B-aligned
        float4 f0 = xv[0], f1 = xv[1], f2 = xv[2], f3 = xv[3], f4 = xv[4];
        float v[20] = {f0.x,f0.y,f0.z,f0.w, f1.x,f1.y,f1.z,f1.w,
                       f2.x,f2.y,f2.z,f2.w, f3.x,f3.y,f3.z,f3.w,
                       f4.x,f4.y,f4.z,f4.w};
        #pragma unroll
        for (int r = 0; r < 2; r++) {
            #pragma unroll
            for (int t = 0; t < 5; t++) {
                float a = 0.f;
                #pragma unroll
                for (int k = 0; k < 10; k++)
                    a = fmaf(v[r*10+k], w2f(wa,wb,wc,wd, k*5+t), a);
                Z[d0+r][t] = a;
            }
        }
    }

    // ---- stage 2: X3 = W1b @ relu(W1 @ Z + B); W1 from LDS, B/W1b from SGPR ----
    f32x8 bw;
    {
        const float* bp = ws + 40;   // record 0, bias part
        asm volatile("s_load_dwordx8 %0, %1, 0x0\n\ts_waitcnt lgkmcnt(0)"
                     : "=&s"(bw) : "s"(bp));
    }
    float X3[15];
    #pragma unroll
    for (int i = 0; i < 15; i++) X3[i] = 0.f;

    for (int e = 0; e < 120; e++) {
        // prefetch next record's bias/W1b (rec 120 is a zero pad)
        f32x8 bwn;
        {
            const float* bpn = ws + (e+1)*48 + 40;
            asm volatile("s_load_dwordx8 %0, %1, 0x0" : "=&s"(bwn) : "s"(bpn));
        }

        const float4* wr = (const float4*)(&sRec[e*48 + p*20]);  // 16B-aligned
        float acc[5] = {0.f,0.f,0.f,0.f,0.f};
        #pragma unroll
        for (int c = 0; c < 5; c++) {
            float4 w = wr[c];
            #pragma unroll
            for (int t = 0; t < 5; t++) {
                acc[t] = fmaf(w.x, Z[c*4+0][t], acc[t]);
                acc[t] = fmaf(w.y, Z[c*4+1][t], acc[t]);
                acc[t] = fmaf(w.z, Z[c*4+2][t], acc[t]);
                acc[t] = fmaf(w.w, Z[c*4+3][t], acc[t]);
            }
        }
        #pragma unroll
        for (int t = 0; t < 5; t++) acc[t] = pair_sum(acc[t]);

        #pragma unroll
        for (int t = 0; t < 5; t++) {
            float h = fmaxf(acc[t] + bw[t], 0.f);
            X3[t]    = fmaf(bw[5], h, X3[t]);
            X3[5+t]  = fmaf(bw[6], h, X3[5+t]);
            X3[10+t] = fmaf(bw[7], h, X3[10+t]);
        }

        asm volatile("s_waitcnt lgkmcnt(0)" : "+s"(bwn));
        bw = bwn;
    }

    // ---- stage 3: attention + output softmax (consts from SGPR) ----
    f32x16 ca, cb; f32x4t cc;
    {
        const float* cp = ws + 5888;
        asm volatile("s_load_dwordx16 %0, %3, 0x0\n\t"
                     "s_load_dwordx16 %1, %3, 0x40\n\t"
                     "s_load_dwordx4  %2, %3, 0x80\n\t"
                     "s_waitcnt lgkmcnt(0)"
                     : "=&s"(ca), "=&s"(cb), "=&s"(cc)
                     : "s"(cp));
    }
    const float lam  = c3f(ca, cb, cc, 33);
    const float olam = 1.f - lam;

    float y[3];
    #pragma unroll
    for (int j = 0; j < 3; j++) {
        float Sr[5];
        #pragma unroll
        for (int t = 0; t < 5; t++) {
            float a = 0.f;
            #pragma unroll
            for (int k = 0; k < 5; k++)
                a = fmaf(X3[j*5+k], c3f(ca, cb, cc, k*5+t), a);
            Sr[t] = a;
        }
        float m = Sr[0];
        #pragma unroll
        for (int t = 1; t < 5; t++) m = fmaxf(m, Sr[t]);
        float ex[5], se = 0.f;
        #pragma unroll
        for (int t = 0; t < 5; t++) { ex[t] = __expf(Sr[t]-m); se += ex[t]; }
        const float inv = 1.f/se;
        float yj = c3f(ca, cb, cc, 30+j);
        #pragma unroll
        for (int t = 0; t < 5; t++) {
            float a  = ex[t]*inv;
            float xc = X3[j*5+t]*(lam + olam*a);
            yj = fmaf(xc, c3f(ca, cb, cc, 25+t), yj);
        }
        y[j] = yj;
    }
    float m  = fmaxf(y[0], fmaxf(y[1], y[2]));
    float e0 = __expf(y[0]-m), e1 = __expf(y[1]-m), e2 = __expf(y[2]-m);
    float inv = 1.f/(e0+e1+e2);
    if (p == 0) {
        float* o = out + (size_t)s*3;
        o[0] = e0*inv; o[1] = e1*inv; o[2] = e2*inv;
    }
}

extern "C" void kernel_launch(void* const* d_in, const int* in_sizes, int n_in,
                              void* d_out, int out_size, void* d_ws, size_t ws_size,
                              hipStream_t stream) {
    const float* x   = (const float*)d_in[0];
    const float* W1  = (const float*)d_in[1];
    const float* W2  = (const float*)d_in[2];
    const float* B   = (const float*)d_in[3];
    const float* Tw1 = (const float*)d_in[4];
    const float* Tw  = (const float*)d_in[5];
    const float* Tw2 = (const float*)d_in[6];
    const float* TB  = (const float*)d_in[7];
    const float* l   = (const float*)d_in[8];
    float* out = (float*)d_out;
    float* ws  = (float*)d_ws;

    hipLaunchKernelGGL(prep_kernel, dim3(1), dim3(NT), 0, stream,
                       W1, W2, B, Tw1, Tw, Tw2, TB, l, ws);

    const int nsamp = in_sizes[0] / 400;
    const int grid  = (nsamp + 127) / 128;
    hipLaunchKernelGGL(btabl_main, dim3(grid), dim3(NT), 0, stream,
                       x, ws, out, nsamp);
}

// Round 3
// 380.589 us; speedup vs baseline: 1.3533x; 1.0780x over previous
//
#include <hip/hip_runtime.h>

// m_btabl — round 3: stage-2 on MFMA (bf16 16x16x32), bias folded via K-augmentation.
//
// prep_kernel (1 block): max_norm scales, then pack into d_ws (floats):
//   [0,3096)     W1 image, bf16 ushort[129*48]: row e, col k:
//                  e<120,k<40 : W1s[e][k];  e<120,40<=k<45 : B[e][k-40];  else 0
//   [3096,3608)  w1b pack f32 [128][4] = {w1b0,w1b1,w1b2,0}  (e>=120 -> 0)
//   [3608,3644)  consts: Wm(25, diag forced 0.2) | W2b(5) | TB(3) | lam | pad
//   [3644,3694)  W2s (50)
//
// btabl_main: 2048 blocks x 320 threads (5 waves), 64 samples/block.
//   stage1: thread (s,c): rows 8c..8c+7 of x -> Z[8][5] f32 -> bf16 -> LDS B-layout
//           [col=5s+t][k=d], + one-hot aug at k=40+t (folds bias).
//   stage2: wave w owns n-tiles 4w..4w+3 (cols 64w..64w+63). M=128 (8 m-tiles),
//           K=48: mfma(A0,B0)+mfma(A1,B1); B1 quads 2,3 zeroed (k=48..63 pad);
//           A overflow reads land on finite bf16 (row 128 zeroed) so 0*A stays 0.
//   epilogue: h=relu(acc) (bias already in GEMM), X3p += w1b*h in C-layout,
//           quad-reduce via shfl_xor(16,32), X3 -> LDS, per-sample attention tail.

typedef short bf16x8 __attribute__((ext_vector_type(8)));
typedef float f32x4v __attribute__((ext_vector_type(4)));

#define NTP 256
#define NTM 320

__device__ __forceinline__ unsigned short f2bf(float f) {
    unsigned int u = __float_as_uint(f);
    u += 0x7FFFu + ((u >> 16) & 1u);   // round-to-nearest-even
    return (unsigned short)(u >> 16);
}

// ---------------- prep kernel ----------------
__device__ __forceinline__ float block_reduce_sum(float v, float* red, int tid) {
    #pragma unroll
    for (int off = 32; off > 0; off >>= 1) v += __shfl_xor(v, off, 64);
    if ((tid & 63) == 0) red[tid >> 6] = v;
    __syncthreads();
    float r = red[0] + red[1] + red[2] + red[3];
    __syncthreads();
    return r;
}

__global__ __launch_bounds__(NTP)
void prep_kernel(const float* __restrict__ W1, const float* __restrict__ W2,
                 const float* __restrict__ B,  const float* __restrict__ Tw1,
                 const float* __restrict__ Tw, const float* __restrict__ Tw2,
                 const float* __restrict__ TB, const float* __restrict__ l,
                 float* __restrict__ ws)
{
    __shared__ float red[4];
    const int tid = threadIdx.x;
    float ss;
    ss = 0.f; for (int i = tid; i < 4800; i += NTP) { float w = W1[i];  ss += w*w; }
    const float n1 = sqrtf(block_reduce_sum(ss, red, tid));
    ss = 0.f; for (int i = tid; i < 50;   i += NTP) { float w = W2[i];  ss += w*w; }
    const float n2 = sqrtf(block_reduce_sum(ss, red, tid));
    ss = 0.f; for (int i = tid; i < 360;  i += NTP) { float w = Tw1[i]; ss += w*w; }
    const float n3 = sqrtf(block_reduce_sum(ss, red, tid));
    ss = 0.f; for (int i = tid; i < 25;   i += NTP) { float w = Tw[i];  ss += w*w; }
    const float n4 = sqrtf(block_reduce_sum(ss, red, tid));
    ss = 0.f; for (int i = tid; i < 5;    i += NTP) { float w = Tw2[i]; ss += w*w; }
    const float n5 = sqrtf(block_reduce_sum(ss, red, tid));

    const float s1 = n1 > 10.f ? 10.f/(1e-8f+n1) : 1.f;
    const float s2 = n2 > 10.f ? 10.f/(1e-8f+n2) : 1.f;
    const float s3 = n3 > 10.f ? 10.f/(1e-8f+n3) : 1.f;
    const float s4 = n4 > 10.f ? 10.f/(1e-8f+n4) : 1.f;
    const float s5 = n5 > 10.f ? 10.f/(1e-8f+n5) : 1.f;

    // W1 image (bf16)
    unsigned short* img = (unsigned short*)ws;
    for (int i = tid; i < 129*48; i += NTP) {
        const int e = i / 48, k = i - e*48;
        float v = 0.f;
        if (e < 120) {
            if (k < 40)      v = W1[e*40 + k] * s1;
            else if (k < 45) v = B[e*5 + (k-40)];      // bias fold (unscaled)
        }
        img[i] = f2bf(v);
    }
    // w1b pack
    for (int i = tid; i < 512; i += NTP) {
        const int e = i >> 2, c = i & 3;
        ws[3096 + i] = (c < 3 && e < 120) ? Tw1[c*120 + e] * s3 : 0.f;
    }
    // consts
    for (int i = tid; i < 36; i += NTP) {
        float v = 0.f;
        if (i < 25)      { int r = i/5, c = i - r*5; v = (r == c) ? 0.2f : Tw[i]*s4; }
        else if (i < 30) v = Tw2[i-25] * s5;
        else if (i < 33) v = TB[i-30];
        else if (i == 33){ float lv = l[0]; v = fminf(fmaxf(lv, 0.f), 1.f); }
        ws[3608 + i] = v;
    }
    // W2s
    for (int i = tid; i < 50; i += NTP) ws[3644 + i] = W2[i] * s2;
}

// ---------------- main kernel ----------------
__global__ __launch_bounds__(NTM)
void btabl_main(const float* __restrict__ x, const float* __restrict__ ws,
                float* __restrict__ out, int nsamp)
{
    __align__(16) __shared__ unsigned short sW1[129*48];       // 12384 B
    __align__(16) __shared__ float          sWp[128*4];        // 2048 B
    __align__(16) __shared__ float          sC[36];            // 144 B
    __align__(16) __shared__ unsigned short sZ[320*48 + 16];   // 30752 B (+overflow pad)
    __align__(16) __shared__ float          sX3[320*3];        // 3840 B

    const int tid = threadIdx.x;

    // ---- stage weights into LDS ----
    {
        const float4* src = (const float4*)ws;
        float4* d1 = (float4*)sW1;
        for (int i = tid; i < 774; i += NTM) d1[i] = src[i];
        float4* d2 = (float4*)sWp;
        for (int i = tid; i < 128; i += NTM) d2[i] = src[774 + i];
        if (tid < 9) ((float4*)sC)[tid] = src[902 + tid];
    }

    // ---- stage 1: Z = x @ W2s -> bf16 LDS (B-operand layout) + one-hot aug ----
    {
        const int sLoc = tid / 5, c = tid - sLoc*5;           // sample, d-chunk
        const int sGlob = blockIdx.x * 64 + sLoc;
        const int sClamp = sGlob < nsamp ? sGlob : (nsamp - 1);
        const float* W2p = ws + 3644;                          // uniform -> s_load
        const float* xs = x + (size_t)sClamp*400 + c*80;       // 8 rows of 10, 16B-aligned

        float Zf[8][5];
        #pragma unroll
        for (int hh = 0; hh < 2; hh++) {                       // 4 rows at a time
            const float4* xv = (const float4*)(xs + hh*40);
            float xf[40];
            #pragma unroll
            for (int i = 0; i < 10; i++) {
                float4 q = xv[i];
                xf[i*4+0] = q.x; xf[i*4+1] = q.y; xf[i*4+2] = q.z; xf[i*4+3] = q.w;
            }
            #pragma unroll
            for (int r = 0; r < 4; r++) {
                #pragma unroll
                for (int t = 0; t < 5; t++) {
                    float a = 0.f;
                    #pragma unroll
                    for (int k = 0; k < 10; k++)
                        a = fmaf(xf[r*10+k], W2p[k*5+t], a);
                    Zf[hh*4+r][t] = a;
                }
            }
        }
        const int colBase = 5 * sLoc;
        #pragma unroll
        for (int t = 0; t < 5; t++) {
            bf16x8 zv;
            #pragma unroll
            for (int r = 0; r < 8; r++) zv[r] = (short)f2bf(Zf[r][t]);
            *(bf16x8*)(sZ + (colBase + t)*48 + c*8) = zv;      // k = 8c..8c+7
        }
        // one-hot aug at k=40..47 for col (5 sLoc + c): 1.0 at k=40+c
        bf16x8 oh = {0,0,0,0,0,0,0,0};
        oh[c] = (short)0x3F80;                                 // bf16 1.0
        *(bf16x8*)(sZ + (colBase + c)*48 + 40) = oh;
    }
    __syncthreads();

    // ---- stage 2: MFMA GEMM + X3 epilogue ----
    const int wave = tid >> 6;
    const int lane = tid & 63;
    const int quad = lane >> 4;
    const int m    = lane & 15;
    const int colBase = wave * 64;

    // preload B fragments for this wave's 4 n-tiles
    bf16x8 Bf[4][2];
    const bf16x8 z8 = {0,0,0,0,0,0,0,0};
    #pragma unroll
    for (int nt = 0; nt < 4; nt++) {
        const int col = colBase + nt*16 + m;
        Bf[nt][0] = *(const bf16x8*)(sZ + col*48 + quad*8);
        bf16x8 b1 = *(const bf16x8*)(sZ + col*48 + 32 + quad*8);  // quads 2,3 overflow
        Bf[nt][1] = (quad >= 2) ? z8 : b1;                         // k>=48 is pad -> 0
    }

    float X3p[4][3];
    #pragma unroll
    for (int nt = 0; nt < 4; nt++)
        #pragma unroll
        for (int j = 0; j < 3; j++) X3p[nt][j] = 0.f;

    const f32x4v zacc = {0.f, 0.f, 0.f, 0.f};
    #pragma unroll
    for (int mt = 0; mt < 8; mt++) {
        const unsigned short* arow = sW1 + (mt*16 + m)*48;
        const bf16x8 A0 = *(const bf16x8*)(arow + quad*8);
        const bf16x8 A1 = *(const bf16x8*)(arow + 32 + quad*8);   // overflow hits finite bf16
        f32x4v wp[4];
        #pragma unroll
        for (int r = 0; r < 4; r++)
            wp[r] = *(const f32x4v*)(sWp + (mt*16 + quad*4 + r)*4);
        #pragma unroll
        for (int nt = 0; nt < 4; nt++) {
            f32x4v acc = __builtin_amdgcn_mfma_f32_16x16x32_bf16(A0, Bf[nt][0], zacc, 0, 0, 0);
            acc = __builtin_amdgcn_mfma_f32_16x16x32_bf16(A1, Bf[nt][1], acc, 0, 0, 0);
            #pragma unroll
            for (int r = 0; r < 4; r++) {
                const float h = fmaxf(acc[r], 0.f);               // bias already folded
                X3p[nt][0] = fmaf(wp[r][0], h, X3p[nt][0]);
                X3p[nt][1] = fmaf(wp[r][1], h, X3p[nt][1]);
                X3p[nt][2] = fmaf(wp[r][2], h, X3p[nt][2]);
            }
        }
    }

    // quad-reduce X3 partials (rows split across quads), write to LDS
    #pragma unroll
    for (int nt = 0; nt < 4; nt++) {
        #pragma unroll
        for (int j = 0; j < 3; j++) {
            float v = X3p[nt][j];
            v += __shfl_xor(v, 16, 64);
            v += __shfl_xor(v, 32, 64);
            X3p[nt][j] = v;
        }
    }
    if (quad == 0) {
        #pragma unroll
        for (int nt = 0; nt < 4; nt++) {
            const int col = colBase + nt*16 + m;
            sX3[col*3 + 0] = X3p[nt][0];
            sX3[col*3 + 1] = X3p[nt][1];
            sX3[col*3 + 2] = X3p[nt][2];
        }
    }
    __syncthreads();

    // ---- stage 3: attention + output softmax, one thread per sample ----
    if (tid < 64) {
        const int sGlob = blockIdx.x * 64 + tid;
        float X3v[3][5];
        #pragma unroll
        for (int t = 0; t < 5; t++)
            #pragma unroll
            for (int j = 0; j < 3; j++)
                X3v[j][t] = sX3[(tid*5 + t)*3 + j];

        const float lam  = sC[33];
        const float olam = 1.f - lam;
        float y[3];
        #pragma unroll
        for (int j = 0; j < 3; j++) {
            float S[5];
            #pragma unroll
            for (int t = 0; t < 5; t++) {
                float a = 0.f;
                #pragma unroll
                for (int k = 0; k < 5; k++)
                    a = fmaf(X3v[j][k], sC[k*5 + t], a);
                S[t] = a;
            }
            float mx = S[0];
            #pragma unroll
            for (int t = 1; t < 5; t++) mx = fmaxf(mx, S[t]);
            float ex[5], se = 0.f;
            #pragma unroll
            for (int t = 0; t < 5; t++) { ex[t] = __expf(S[t] - mx); se += ex[t]; }
            const float inv = 1.f / se;
            float yj = sC[30 + j];
            #pragma unroll
            for (int t = 0; t < 5; t++) {
                const float a  = ex[t] * inv;
                const float xc = X3v[j][t] * (lam + olam * a);
                yj = fmaf(xc, sC[25 + t], yj);
            }
            y[j] = yj;
        }
        const float mx = fmaxf(y[0], fmaxf(y[1], y[2]));
        const float e0 = __expf(y[0]-mx), e1 = __expf(y[1]-mx), e2 = __expf(y[2]-mx);
        const float inv = 1.f / (e0 + e1 + e2);
        if (sGlob < nsamp) {
            float* o = out + (size_t)sGlob*3;
            o[0] = e0*inv; o[1] = e1*inv; o[2] = e2*inv;
        }
    }
}

extern "C" void kernel_launch(void* const* d_in, const int* in_sizes, int n_in,
                              void* d_out, int out_size, void* d_ws, size_t ws_size,
                              hipStream_t stream) {
    const float* x   = (const float*)d_in[0];
    const float* W1  = (const float*)d_in[1];
    const float* W2  = (const float*)d_in[2];
    const float* B   = (const float*)d_in[3];
    const float* Tw1 = (const float*)d_in[4];
    const float* Tw  = (const float*)d_in[5];
    const float* Tw2 = (const float*)d_in[6];
    const float* TB  = (const float*)d_in[7];
    const float* l   = (const float*)d_in[8];
    float* out = (float*)d_out;
    float* ws  = (float*)d_ws;

    hipLaunchKernelGGL(prep_kernel, dim3(1), dim3(NTP), 0, stream,
                       W1, W2, B, Tw1, Tw, Tw2, TB, l, ws);

    const int nsamp = in_sizes[0] / 400;
    const int grid  = (nsamp + 63) / 64;
    hipLaunchKernelGGL(btabl_main, dim3(grid), dim3(NTM), 0, stream,
                       x, ws, out, nsamp);
}